// Round 1
// baseline (381.067 us; speedup 1.0000x reference)
//
#include <hip/hip_runtime.h>
#include <math.h>

#define C_IN  512
#define C_OUT 4
#define WDIM  128
#define HW    16384   // 128*128 pixels per image
#define BATCH 8

// Kernel 1: ke[b][c][o] = ((w[b]·affine_w[:,c] + affine_b[c]) / sqrt(512)) * k2d[c][o]
// 32 blocks x 128 threads: blockIdx -> (b, c-quarter); thread -> c within quarter.
__global__ __launch_bounds__(128) void ke_kernel(
    const float* __restrict__ w, const float* __restrict__ aw,
    const float* __restrict__ ab, const float* __restrict__ k2d,
    float* __restrict__ ke)
{
    const int b = blockIdx.x >> 2;
    const int c = ((blockIdx.x & 3) << 7) | threadIdx.x;
    const float* __restrict__ wr = w + b * WDIM;   // wave-uniform row -> s_load
    float s = 0.f;
    #pragma unroll 8
    for (int j = 0; j < WDIM; ++j)
        s = fmaf(wr[j], aw[j * C_IN + c], s);       // aw column read: coalesced across lanes
    s = (s + ab[c]) * 0.04419417382415922f;         // 1/sqrt(512)
    const float4 kk = ((const float4*)k2d)[c];      // kernel[0,0,c,0..3]
    float4 o;
    o.x = s * kk.x; o.y = s * kk.y; o.z = s * kk.z; o.w = s * kk.w;
    ((float4*)ke)[b * C_IN + c] = o;
}

// Kernel 2: out[pixel][o] = tanh( sum_c x[pixel][c] * ke[b][c][o] + bias[o] )
// Thread-per-pixel; 512 blocks x 256 threads; b uniform per block (64 blocks/image).
__global__ __launch_bounds__(256) void torgb_kernel(
    const float* __restrict__ x, const float* __restrict__ ke,
    const float* __restrict__ bias, float* __restrict__ out)
{
    const int b = blockIdx.x >> 6;                        // 64 blocks per image
    const int pix_in_img = ((blockIdx.x & 63) << 8) | threadIdx.x;
    const long pixel = (long)b * HW + pix_in_img;

    const float4* __restrict__ xp = (const float4*)(x + pixel * (long)C_IN);
    const float4* __restrict__ kp = (const float4*)(ke + (size_t)b * C_IN * C_OUT); // uniform -> s_load

    float a0 = 0.f, a1 = 0.f, a2 = 0.f, a3 = 0.f;
    #pragma unroll 8
    for (int k = 0; k < C_IN / 4; ++k) {
        const float4 xv = xp[k];          // per-lane contiguous 2KB stream, all bytes consumed
        const float4 k0 = kp[4*k + 0];    // ke rows for channels 4k..4k+3 (each float4 = 4 outputs)
        const float4 k1 = kp[4*k + 1];
        const float4 k2 = kp[4*k + 2];
        const float4 k3 = kp[4*k + 3];
        a0 = fmaf(xv.x, k0.x, fmaf(xv.y, k1.x, fmaf(xv.z, k2.x, fmaf(xv.w, k3.x, a0))));
        a1 = fmaf(xv.x, k0.y, fmaf(xv.y, k1.y, fmaf(xv.z, k2.y, fmaf(xv.w, k3.y, a1))));
        a2 = fmaf(xv.x, k0.z, fmaf(xv.y, k1.z, fmaf(xv.z, k2.z, fmaf(xv.w, k3.z, a2))));
        a3 = fmaf(xv.x, k0.w, fmaf(xv.y, k1.w, fmaf(xv.z, k2.w, fmaf(xv.w, k3.w, a3))));
    }

    const float4 bb = *(const float4*)bias;               // uniform
    float4 o;
    o.x = tanhf(a0 + bb.x);
    o.y = tanhf(a1 + bb.y);
    o.z = tanhf(a2 + bb.z);
    o.w = tanhf(a3 + bb.w);
    ((float4*)out)[pixel] = o;                            // coalesced 16B/lane
}

extern "C" void kernel_launch(void* const* d_in, const int* in_sizes, int n_in,
                              void* d_out, int out_size, void* d_ws, size_t ws_size,
                              hipStream_t stream) {
    const float* x    = (const float*)d_in[0];   // [8,128,128,512]
    const float* w    = (const float*)d_in[1];   // [8,128]
    const float* aw   = (const float*)d_in[2];   // [128,512]
    const float* ab   = (const float*)d_in[3];   // [512]
    const float* kk   = (const float*)d_in[4];   // [1,1,512,4]
    const float* bias = (const float*)d_in[5];   // [4]
    float* out = (float*)d_out;                  // [8,128,128,4] fp32
    float* ke  = (float*)d_ws;                   // 8*512*4 floats = 64 KB scratch

    hipLaunchKernelGGL(ke_kernel, dim3(BATCH * 4), dim3(128), 0, stream,
                       w, aw, ab, kk, ke);
    hipLaunchKernelGGL(torgb_kernel, dim3(BATCH * 64), dim3(256), 0, stream,
                       x, ke, bias, out);
}

// Round 2
// 376.282 us; speedup vs baseline: 1.0127x; 1.0127x over previous
//
#include <hip/hip_runtime.h>
#include <math.h>

#define C_IN  512
#define C_OUT 4
#define WDIM  128
#define HW    16384   // 128*128 pixels per image
#define BATCH 8

// ---------------- Kernel 1: per-image effective 1x1 kernel ----------------
// ke[b][c] (float4 over outputs) = ((w[b]·affine_w[:,c] + affine_b[c]) / sqrt(512)) * k2d[c][:]
__global__ __launch_bounds__(128) void ke_kernel(
    const float* __restrict__ w, const float* __restrict__ aw,
    const float* __restrict__ ab, const float* __restrict__ k2d,
    float* __restrict__ ke)
{
    const int b = blockIdx.x >> 2;
    const int c = ((blockIdx.x & 3) << 7) | threadIdx.x;
    const float* __restrict__ wr = w + b * WDIM;   // wave-uniform row
    float s = 0.f;
    #pragma unroll 8
    for (int j = 0; j < WDIM; ++j)
        s = fmaf(wr[j], aw[j * C_IN + c], s);       // coalesced across lanes
    s = (s + ab[c]) * 0.04419417382415922f;         // 1/sqrt(512)
    const float4 kk = ((const float4*)k2d)[c];
    float4 o;
    o.x = s * kk.x; o.y = s * kk.y; o.z = s * kk.z; o.w = s * kk.w;
    ((float4*)ke)[b * C_IN + c] = o;
}

// ---------------- wave-wide sum: DPP within 16, swizzle/bpermute across ----------------
__device__ __forceinline__ float wave_sum(float v) {
    int t;
    // row_ror:8  — lane i += lane (i+8)%16 within its row of 16
    t = __builtin_amdgcn_update_dpp(0, __float_as_int(v), 0x128, 0xF, 0xF, true);
    v += __int_as_float(t);
    // row_ror:4
    t = __builtin_amdgcn_update_dpp(0, __float_as_int(v), 0x124, 0xF, 0xF, true);
    v += __int_as_float(t);
    // quad_perm [2,3,0,1] = xor2
    t = __builtin_amdgcn_update_dpp(0, __float_as_int(v), 0x4E, 0xF, 0xF, true);
    v += __int_as_float(t);
    // quad_perm [1,0,3,2] = xor1
    t = __builtin_amdgcn_update_dpp(0, __float_as_int(v), 0xB1, 0xF, 0xF, true);
    v += __int_as_float(t);
    // xor16 via ds_swizzle (BitMode: offset = xor<<10 | and 0x1F)
    v += __int_as_float(__builtin_amdgcn_ds_swizzle(__float_as_int(v), 0x401F));
    // cross-32 half (ds_bpermute across full wave64)
    v += __shfl_xor(v, 32, 64);
    return v;
}

__device__ __forceinline__ float fast_tanh(float x) {
    // tanh(x) = 1 - 2/(e^{2x}+1); exact at +/-inf, ~1e-6 rel error (threshold 2e-2)
    float e = __expf(2.0f * x);
    return 1.0f - 2.0f / (e + 1.0f);
}

// ---------------- Kernel 2: wave-per-pixel, split-K over lanes ----------------
// Lane l owns channels [4l..4l+3] and [256+4l..256+4l+3]:
//  - the two x float4 loads per pixel are each a perfectly coalesced,
//    contiguous 1 KiB wave transaction (lane l -> bytes 16l of each half-row)
//  - each lane keeps its 8 ke rows (32 VGPRs) for the whole kernel
__global__ __launch_bounds__(256) void torgb_kernel(
    const float* __restrict__ x, const float* __restrict__ ke,
    const float* __restrict__ bias, float* __restrict__ out)
{
    const int lane   = threadIdx.x & 63;
    const int wave_g = (blockIdx.x << 2) | (threadIdx.x >> 6);   // 4 waves/block
    const int pix_base = wave_g * 16;                            // 16 px per wave
    const int b = pix_base >> 14;                                // uniform per wave (16 | 16384)

    const float4* __restrict__ kp = (const float4*)ke + (size_t)b * C_IN;
    float4 kr0[4], kr1[4];
    #pragma unroll
    for (int j = 0; j < 4; ++j) {
        kr0[j] = kp[4 * lane + j];          // channels 4l..4l+3
        kr1[j] = kp[256 + 4 * lane + j];    // channels 256+4l..256+4l+3
    }
    const float4 bb = *(const float4*)bias;
    float4* __restrict__ out4 = (float4*)out;

    #pragma unroll 2
    for (int i = 0; i < 16; ++i) {
        const int pix = pix_base + i;
        const float4* __restrict__ xp = (const float4*)(x + (size_t)pix * C_IN);
        const float4 xa = xp[lane];        // coalesced: bytes [16l .. 16l+15] of row
        const float4 xb = xp[64 + lane];   // coalesced: second KiB of row

        float a0 = 0.f, a1 = 0.f, a2 = 0.f, a3 = 0.f;
        a0 = fmaf(xa.x, kr0[0].x, fmaf(xa.y, kr0[1].x, fmaf(xa.z, kr0[2].x, fmaf(xa.w, kr0[3].x, a0))));
        a1 = fmaf(xa.x, kr0[0].y, fmaf(xa.y, kr0[1].y, fmaf(xa.z, kr0[2].y, fmaf(xa.w, kr0[3].y, a1))));
        a2 = fmaf(xa.x, kr0[0].z, fmaf(xa.y, kr0[1].z, fmaf(xa.z, kr0[2].z, fmaf(xa.w, kr0[3].z, a2))));
        a3 = fmaf(xa.x, kr0[0].w, fmaf(xa.y, kr0[1].w, fmaf(xa.z, kr0[2].w, fmaf(xa.w, kr0[3].w, a3))));
        a0 = fmaf(xb.x, kr1[0].x, fmaf(xb.y, kr1[1].x, fmaf(xb.z, kr1[2].x, fmaf(xb.w, kr1[3].x, a0))));
        a1 = fmaf(xb.x, kr1[0].y, fmaf(xb.y, kr1[1].y, fmaf(xb.z, kr1[2].y, fmaf(xb.w, kr1[3].y, a1))));
        a2 = fmaf(xb.x, kr1[0].z, fmaf(xb.y, kr1[1].z, fmaf(xb.z, kr1[2].z, fmaf(xb.w, kr1[3].z, a2))));
        a3 = fmaf(xb.x, kr1[0].w, fmaf(xb.y, kr1[1].w, fmaf(xb.z, kr1[2].w, fmaf(xb.w, kr1[3].w, a3))));

        a0 = wave_sum(a0);
        a1 = wave_sum(a1);
        a2 = wave_sum(a2);
        a3 = wave_sum(a3);

        if (lane == 0) {
            float4 o;
            o.x = fast_tanh(a0 + bb.x);
            o.y = fast_tanh(a1 + bb.y);
            o.z = fast_tanh(a2 + bb.z);
            o.w = fast_tanh(a3 + bb.w);
            out4[pix] = o;
        }
    }
}

extern "C" void kernel_launch(void* const* d_in, const int* in_sizes, int n_in,
                              void* d_out, int out_size, void* d_ws, size_t ws_size,
                              hipStream_t stream) {
    const float* x    = (const float*)d_in[0];   // [8,128,128,512]
    const float* w    = (const float*)d_in[1];   // [8,128]
    const float* aw   = (const float*)d_in[2];   // [128,512]
    const float* ab   = (const float*)d_in[3];   // [512]
    const float* kk   = (const float*)d_in[4];   // [1,1,512,4]
    const float* bias = (const float*)d_in[5];   // [4]
    float* out = (float*)d_out;                  // [8,128,128,4] fp32
    float* ke  = (float*)d_ws;                   // 8*512*4 floats = 64 KB scratch

    hipLaunchKernelGGL(ke_kernel, dim3(BATCH * 4), dim3(128), 0, stream,
                       w, aw, ab, kk, ke);
    // 131072 pixels / (16 px/wave * 4 waves/block) = 2048 blocks
    hipLaunchKernelGGL(torgb_kernel, dim3(2048), dim3(256), 0, stream,
                       x, ke, bias, out);
}